// Round 2
// baseline (952.529 us; speedup 1.0000x reference)
//
#include <hip/hip_runtime.h>
#include <hip/hip_bf16.h>
#include <stdint.h>

typedef unsigned short u16;
typedef __bf16 bf16x8 __attribute__((ext_vector_type(8)));
typedef unsigned short u16x8 __attribute__((ext_vector_type(8)));
typedef float f32x4 __attribute__((ext_vector_type(4)));

__device__ __forceinline__ float bf2f(u16 h) {
  union { uint32_t u; float f; } x;
  x.u = ((uint32_t)h) << 16;
  return x.f;
}
__device__ __forceinline__ u16 f2bf(float f) {
  union { float f; uint32_t u; } x;
  x.f = f;
  uint32_t r = x.u + 0x7FFFu + ((x.u >> 16) & 1u);  // round-to-nearest-even
  return (u16)(r >> 16);
}

// async global->LDS, 16B per lane. LDS dest must be wave-uniform base + lane*16.
__device__ __forceinline__ void gload_lds16(const u16* g, u16* l) {
  __builtin_amdgcn_global_load_lds(
      (const __attribute__((address_space(1))) uint32_t*)g,
      (__attribute__((address_space(3))) uint32_t*)l, 16, 0, 0);
}

// fp32 -> bf16 elementwise, 8 elems/thread. n8 = n/8.
__global__ __launch_bounds__(256) void cvt_f32_bf16(
    const float* __restrict__ in, u16* __restrict__ out, int n8) {
  int i = blockIdx.x * 256 + threadIdx.x;
  if (i >= n8) return;
  const float4* p = (const float4*)in + (size_t)i * 2;
  float4 a = p[0], b = p[1];
  u16x8 o;
  o[0] = f2bf(a.x); o[1] = f2bf(a.y); o[2] = f2bf(a.z); o[3] = f2bf(a.w);
  o[4] = f2bf(b.x); o[5] = f2bf(b.y); o[6] = f2bf(b.z); o[7] = f2bf(b.w);
  ((u16x8*)out)[i] = o;
}

// C[m,n] = scale * sum_k A[m,k] * B[n,k]   (bf16 in, OT out, fp32 accum)
// Block = 256 threads (4 waves, 2x2), tile 128x128, BK=32, MFMA 16x16x32 bf16.
// M, N multiples of 128; K multiple of 32. Grid: (N/128, M/128).
template <typename OT>
__global__ __launch_bounds__(256) void gemm_bt(
    const u16* __restrict__ A, int lda,
    const u16* __restrict__ B, int ldb,
    OT* __restrict__ C, int ldc,
    int K, float scale) {
  __shared__ __align__(16) u16 As[128 * 32];
  __shared__ __align__(16) u16 Bs[128 * 32];
  const int tid  = threadIdx.x;
  const int m0   = blockIdx.y * 128;
  const int n0   = blockIdx.x * 128;
  const int wave = tid >> 6;
  const int lane = tid & 63;
  const int wm   = (wave >> 1) * 64;  // wave row offset in tile
  const int wn   = (wave & 1) * 64;   // wave col offset in tile
  const int l15  = lane & 15;
  const int quad = lane >> 4;

  f32x4 acc[4][4];
#pragma unroll
  for (int i = 0; i < 4; ++i)
#pragma unroll
    for (int j = 0; j < 4; ++j) acc[i][j] = f32x4{0.f, 0.f, 0.f, 0.f};

  // Staging: tile row-major [128][32] in LDS; thread t's 16B chunk:
  // row = t>>2 (+64 for second half), col = (t&3)*8. Lane-contiguous LDS dests.
  const u16* gA0 = A + (size_t)(m0 + (tid >> 2)) * lda + (tid & 3) * 8;
  const u16* gA1 = A + (size_t)(m0 + 64 + (tid >> 2)) * lda + (tid & 3) * 8;
  const u16* gB0 = B + (size_t)(n0 + (tid >> 2)) * ldb + (tid & 3) * 8;
  const u16* gB1 = B + (size_t)(n0 + 64 + (tid >> 2)) * ldb + (tid & 3) * 8;
  u16* lA0 = As + tid * 8;
  u16* lA1 = As + (256 + tid) * 8;
  u16* lB0 = Bs + tid * 8;
  u16* lB1 = Bs + (256 + tid) * 8;

  for (int k0 = 0; k0 < K; k0 += 32) {
    __syncthreads();  // previous iter's LDS reads done before overwrite
    gload_lds16(gA0 + k0, lA0);
    gload_lds16(gA1 + k0, lA1);
    gload_lds16(gB0 + k0, lB0);
    gload_lds16(gB1 + k0, lB1);
    __syncthreads();  // implies s_waitcnt vmcnt(0): staging landed

    u16x8 a[4], b[4];
#pragma unroll
    for (int i = 0; i < 4; ++i)
      a[i] = *(const u16x8*)(As + (wm + i * 16 + l15) * 32 + quad * 8);
#pragma unroll
    for (int j = 0; j < 4; ++j)
      b[j] = *(const u16x8*)(Bs + (wn + j * 16 + l15) * 32 + quad * 8);
#pragma unroll
    for (int i = 0; i < 4; ++i)
#pragma unroll
      for (int j = 0; j < 4; ++j)
        acc[i][j] = __builtin_amdgcn_mfma_f32_16x16x32_bf16(
            __builtin_bit_cast(bf16x8, a[i]), __builtin_bit_cast(bf16x8, b[j]),
            acc[i][j], 0, 0, 0);
  }

  // C/D layout (m89-verified): col = lane&15, row = (lane>>4)*4 + reg
#pragma unroll
  for (int i = 0; i < 4; ++i) {
    const int row0 = m0 + wm + i * 16 + quad * 4;
#pragma unroll
    for (int j = 0; j < 4; ++j) {
      const int col = n0 + wn + j * 16 + l15;
#pragma unroll
      for (int r = 0; r < 4; ++r) {
        float v = acc[i][j][r] * scale;
        if constexpr (__is_same(OT, float))
          C[(size_t)(row0 + r) * ldc + col] = v;
        else
          C[(size_t)(row0 + r) * ldc + col] = f2bf(v);
      }
    }
  }
}

// In-place row softmax on [nrows x 4096] bf16, one block (256 thr) per row.
__global__ __launch_bounds__(256) void softmax_rows(u16* __restrict__ S, int n) {
  const int row  = blockIdx.x;
  u16* p = S + (size_t)row * n;
  const int tid  = threadIdx.x;
  const int lane = tid & 63;
  const int wave = tid >> 6;

  u16x8 h0 = *(const u16x8*)(p + tid * 16);
  u16x8 h1 = *(const u16x8*)(p + tid * 16 + 8);
  float v[16];
#pragma unroll
  for (int j = 0; j < 8; ++j) {
    v[j]     = bf2f(h0[j]);
    v[8 + j] = bf2f(h1[j]);
  }
  float m = v[0];
#pragma unroll
  for (int j = 1; j < 16; ++j) m = fmaxf(m, v[j]);
  for (int o = 32; o > 0; o >>= 1) m = fmaxf(m, __shfl_xor(m, o, 64));
  __shared__ float redm[4];
  __shared__ float reds[4];
  if (lane == 0) redm[wave] = m;
  __syncthreads();
  m = fmaxf(fmaxf(redm[0], redm[1]), fmaxf(redm[2], redm[3]));

  float s = 0.f;
#pragma unroll
  for (int j = 0; j < 16; ++j) {
    v[j] = __expf(v[j] - m);
    s += v[j];
  }
  for (int o = 32; o > 0; o >>= 1) s += __shfl_xor(s, o, 64);
  if (lane == 0) reds[wave] = s;
  __syncthreads();
  s = reds[0] + reds[1] + reds[2] + reds[3];
  const float inv = 1.f / s;

  u16x8 o0, o1;
#pragma unroll
  for (int j = 0; j < 8; ++j) {
    o0[j] = f2bf(v[j] * inv);
    o1[j] = f2bf(v[8 + j] * inv);
  }
  *(u16x8*)(p + tid * 16)     = o0;
  *(u16x8*)(p + tid * 16 + 8) = o1;
}

// Vt[d, s] = V[s, d].  V: [4096 x 1024] bf16 rows stride ldv; Vt: [1024 x 4096].
__global__ __launch_bounds__(256) void transpose_v(
    const u16* __restrict__ V, int ldv, u16* __restrict__ Vt, int ldt) {
  __shared__ u16 T[64][65];
  const int d0 = blockIdx.x * 64;
  const int s0 = blockIdx.y * 64;
  const int tid = threadIdx.x;
  const int c = tid & 63;
  const int rbase = (tid >> 6) * 16;
#pragma unroll
  for (int r = 0; r < 16; ++r)
    T[rbase + r][c] = V[(size_t)(s0 + rbase + r) * ldv + d0 + c];
  __syncthreads();
#pragma unroll
  for (int r = 0; r < 16; ++r)
    Vt[(size_t)(d0 + rbase + r) * ldt + s0 + c] = T[c][rbase + r];
}

extern "C" void kernel_launch(void* const* d_in, const int* in_sizes, int n_in,
                              void* d_out, int out_size, void* d_ws, size_t ws_size,
                              hipStream_t stream) {
  // Reference dtypes: fp32 in, fp32 out. bf16 internally for MFMA.
  const float* x    = (const float*)d_in[0];  // [B*S, D]
  const float* Wqkv = (const float*)d_in[1];  // [3D, D]
  const float* Wo   = (const float*)d_in[2];  // [D, D]
  float* out = (float*)d_out;                 // [B*S, D]

  const int Bn = 4, S = 4096, D = 1024;
  const int M = Bn * S;  // 16384
  const int E = 3 * D;   // 3072

  char* ws = (char*)d_ws;
  u16* qkv   = (u16*)ws;                                  //  96 MB [M x E]
  u16* Sbuf  = (u16*)(ws + (size_t)100663296);            //  32 MB [S x S] per-batch reuse
  u16* Vt    = (u16*)(ws + (size_t)134217728);            //   8 MB [D x S]
  u16* xb    = (u16*)(ws + (size_t)142606336);            //  32 MB [M x D]; aliased w/ attn
  u16* attn  = xb;                                        //  (xb dead after QKV proj)
  u16* Wqkvb = (u16*)(ws + (size_t)176160768);            //   6 MB [E x D]
  u16* Wob   = (u16*)(ws + (size_t)182452224);            //   2 MB [D x D]
  // total ws used: 176 MB

  // 0) fp32 -> bf16 converts
  cvt_f32_bf16<<<(M * D / 8 + 255) / 256, 256, 0, stream>>>(x, xb, M * D / 8);
  cvt_f32_bf16<<<(E * D / 8 + 255) / 256, 256, 0, stream>>>(Wqkv, Wqkvb, E * D / 8);
  cvt_f32_bf16<<<(D * D / 8 + 255) / 256, 256, 0, stream>>>(Wo, Wob, D * D / 8);

  // 1) QKV projection: qkv = xb @ Wqkvb^T   [16384 x 3072]
  gemm_bt<u16><<<dim3(E / 128, M / 128), 256, 0, stream>>>(xb, D, Wqkvb, D, qkv, E, D, 1.0f);

  const float scl = 0.03125f;  // 1/sqrt(1024)
  for (int b = 0; b < Bn; ++b) {
    const u16* Qb = qkv + (size_t)b * S * E;
    const u16* Kb = Qb + D;
    const u16* Vb = Qb + 2 * D;
    // 2) S = (Q @ K^T) / 32  [4096 x 4096]
    gemm_bt<u16><<<dim3(S / 128, S / 128), 256, 0, stream>>>(Qb, E, Kb, E, Sbuf, S, D, scl);
    // 3) P = softmax(S) row-wise, in place
    softmax_rows<<<S, 256, 0, stream>>>(Sbuf, S);
    // 4) Vt = V^T  [1024 x 4096]
    transpose_v<<<dim3(D / 64, S / 64), 256, 0, stream>>>(Vb, E, Vt, S);
    // 5) attn_b = P @ V = P @ (Vt)^T  [4096 x 1024]
    gemm_bt<u16><<<dim3(D / 128, S / 128), 256, 0, stream>>>(Sbuf, S, Vt, S,
                                                             attn + (size_t)b * S * D, D, S, 1.0f);
  }
  // 6) out = attn @ Wo^T  [16384 x 1024]  -> fp32
  gemm_bt<float><<<dim3(D / 128, M / 128), 256, 0, stream>>>(attn, D, Wob, D, out, D, D, 1.0f);
}

// Round 3
// 851.821 us; speedup vs baseline: 1.1182x; 1.1182x over previous
//
#include <hip/hip_runtime.h>
#include <hip/hip_bf16.h>
#include <stdint.h>

typedef unsigned short u16;
typedef __bf16 bf16x8 __attribute__((ext_vector_type(8)));
typedef unsigned short u16x8 __attribute__((ext_vector_type(8)));
typedef float f32x4 __attribute__((ext_vector_type(4)));

__device__ __forceinline__ float bf2f(u16 h) {
  union { uint32_t u; float f; } x;
  x.u = ((uint32_t)h) << 16;
  return x.f;
}
__device__ __forceinline__ u16 f2bf(float f) {
  union { float f; uint32_t u; } x;
  x.f = f;
  uint32_t r = x.u + 0x7FFFu + ((x.u >> 16) & 1u);  // round-to-nearest-even
  return (u16)(r >> 16);
}

// async global->LDS, 16B per lane. LDS dest must be wave-uniform base + lane*16.
__device__ __forceinline__ void gload_lds16(const u16* g, u16* l) {
  __builtin_amdgcn_global_load_lds(
      (const __attribute__((address_space(1))) uint32_t*)g,
      (__attribute__((address_space(3))) uint32_t*)l, 16, 0, 0);
}

// fp32 -> bf16 elementwise, 8 elems/thread.
__global__ __launch_bounds__(256) void cvt_f32_bf16(
    const float* __restrict__ in, u16* __restrict__ out, int n8) {
  int i = blockIdx.x * 256 + threadIdx.x;
  if (i >= n8) return;
  const float4* p = (const float4*)in + (size_t)i * 2;
  float4 a = p[0], b = p[1];
  u16x8 o;
  o[0] = f2bf(a.x); o[1] = f2bf(a.y); o[2] = f2bf(a.z); o[3] = f2bf(a.w);
  o[4] = f2bf(b.x); o[5] = f2bf(b.y); o[6] = f2bf(b.z); o[7] = f2bf(b.w);
  ((u16x8*)out)[i] = o;
}

// C[z][m,n] = epi( scale * sum_k A[z][m,k] * B[z][n,k] )
// EPI: 0 = plain, 1 = exp (unnormalized softmax), 2 = divide by rs[z*4096+row].
// bf16 in, OT out, fp32 accum. 256 thr (2x2 waves), tile 128x128, BK=64 (m97
// recipe: 32 MFMAs per barrier pair, 32 KB LDS). M,N mult of 128, K mult of 64.
template <typename OT, int EPI>
__global__ __launch_bounds__(256) void gemm_bt(
    const u16* __restrict__ A, int lda, long zsA,
    const u16* __restrict__ B, int ldb, long zsB,
    OT* __restrict__ C, int ldc, long zsC,
    int K, float scale, const float* __restrict__ rs) {
  const int z = blockIdx.z;
  A += (long)z * zsA;
  B += (long)z * zsB;
  C += (long)z * zsC;
  if constexpr (EPI == 2) rs += (long)z * 4096;  // per-batch row stride = S

  __shared__ __align__(16) u16 As[2 * 128 * 32];  // [s][row][32]
  __shared__ __align__(16) u16 Bs[2 * 128 * 32];
  const int tid  = threadIdx.x;
  const int m0   = blockIdx.y * 128;
  const int n0   = blockIdx.x * 128;
  const int wave = tid >> 6;
  const int lane = tid & 63;
  const int wm   = (wave >> 1) * 64;
  const int wn   = (wave & 1) * 64;
  const int l15  = lane & 15;
  const int quad = lane >> 4;

  f32x4 acc[4][4];
#pragma unroll
  for (int i = 0; i < 4; ++i)
#pragma unroll
    for (int j = 0; j < 4; ++j) acc[i][j] = f32x4{0.f, 0.f, 0.f, 0.f};

  // Staging: per k-stage s, tile row-major [128][32]. Thread t's 16B chunk:
  // idx = t (+256), row = idx/4, col = (idx%4)*8. Lane-contiguous LDS dests.
  const u16* gA0 = A + (size_t)(m0 + (tid >> 2)) * lda + (tid & 3) * 8;
  const u16* gA1 = A + (size_t)(m0 + 64 + (tid >> 2)) * lda + (tid & 3) * 8;
  const u16* gB0 = B + (size_t)(n0 + (tid >> 2)) * ldb + (tid & 3) * 8;
  const u16* gB1 = B + (size_t)(n0 + 64 + (tid >> 2)) * ldb + (tid & 3) * 8;
  u16* lA0 = As + tid * 8;
  u16* lA1 = As + (256 + tid) * 8;
  u16* lB0 = Bs + tid * 8;
  u16* lB1 = Bs + (256 + tid) * 8;

  for (int k0 = 0; k0 < K; k0 += 64) {
    __syncthreads();  // previous iter's LDS reads done before overwrite
#pragma unroll
    for (int s = 0; s < 2; ++s) {
      gload_lds16(gA0 + k0 + s * 32, lA0 + s * 4096);
      gload_lds16(gA1 + k0 + s * 32, lA1 + s * 4096);
      gload_lds16(gB0 + k0 + s * 32, lB0 + s * 4096);
      gload_lds16(gB1 + k0 + s * 32, lB1 + s * 4096);
    }
    __syncthreads();  // staging landed (vmcnt(0) drained by barrier semantics)

#pragma unroll
    for (int s = 0; s < 2; ++s) {
      u16x8 a[4], b[4];
#pragma unroll
      for (int i = 0; i < 4; ++i)
        a[i] = *(const u16x8*)(As + s * 4096 + (wm + i * 16 + l15) * 32 + quad * 8);
#pragma unroll
      for (int j = 0; j < 4; ++j)
        b[j] = *(const u16x8*)(Bs + s * 4096 + (wn + j * 16 + l15) * 32 + quad * 8);
#pragma unroll
      for (int i = 0; i < 4; ++i)
#pragma unroll
        for (int j = 0; j < 4; ++j)
          acc[i][j] = __builtin_amdgcn_mfma_f32_16x16x32_bf16(
              __builtin_bit_cast(bf16x8, a[i]), __builtin_bit_cast(bf16x8, b[j]),
              acc[i][j], 0, 0, 0);
    }
  }

  // C/D layout (m89-verified): col = lane&15, row = (lane>>4)*4 + reg
#pragma unroll
  for (int i = 0; i < 4; ++i) {
    const int row0 = m0 + wm + i * 16 + quad * 4;
#pragma unroll
    for (int r = 0; r < 4; ++r) {
      float mul = scale;
      if constexpr (EPI == 2) mul = scale * (1.0f / rs[row0 + r]);
      const size_t rowoff = (size_t)(row0 + r) * ldc;
#pragma unroll
      for (int j = 0; j < 4; ++j) {
        const int col = n0 + wn + j * 16 + l15;
        float v = acc[i][j][r] * mul;
        if constexpr (EPI == 1) v = __expf(v);
        if constexpr (__is_same(OT, float))
          C[rowoff + col] = v;
        else
          C[rowoff + col] = f2bf(v);
      }
    }
  }
}

// rs[z*4096+row] = sum of P[z][row][0..4095] (bf16), read-only.
__global__ __launch_bounds__(256) void rowsum_rows(
    const u16* __restrict__ P, long zsP, float* __restrict__ rs) {
  const int row = blockIdx.x;
  const int z   = blockIdx.y;
  const u16* p = P + (long)z * zsP + (size_t)row * 4096;
  const int tid  = threadIdx.x;
  const int lane = tid & 63;
  const int wave = tid >> 6;

  u16x8 h0 = *(const u16x8*)(p + tid * 16);
  u16x8 h1 = *(const u16x8*)(p + tid * 16 + 8);
  float s = 0.f;
#pragma unroll
  for (int j = 0; j < 8; ++j) s += bf2f(h0[j]) + bf2f(h1[j]);
  for (int o = 32; o > 0; o >>= 1) s += __shfl_xor(s, o, 64);
  __shared__ float red[4];
  if (lane == 0) red[wave] = s;
  __syncthreads();
  if (tid == 0) rs[(size_t)z * 4096 + row] = red[0] + red[1] + red[2] + red[3];
}

// Vt[z][d, s] = V[z][s, d].
__global__ __launch_bounds__(256) void transpose_v(
    const u16* __restrict__ V, int ldv, long zsV,
    u16* __restrict__ Vt, int ldt, long zsT) {
  const int z = blockIdx.z;
  V  += (long)z * zsV;
  Vt += (long)z * zsT;
  __shared__ u16 T[64][65];
  const int d0 = blockIdx.x * 64;
  const int s0 = blockIdx.y * 64;
  const int tid = threadIdx.x;
  const int c = tid & 63;
  const int rbase = (tid >> 6) * 16;
#pragma unroll
  for (int r = 0; r < 16; ++r)
    T[rbase + r][c] = V[(size_t)(s0 + rbase + r) * ldv + d0 + c];
  __syncthreads();
#pragma unroll
  for (int r = 0; r < 16; ++r)
    Vt[(size_t)(d0 + rbase + r) * ldt + s0 + c] = T[c][rbase + r];
}

extern "C" void kernel_launch(void* const* d_in, const int* in_sizes, int n_in,
                              void* d_out, int out_size, void* d_ws, size_t ws_size,
                              hipStream_t stream) {
  const float* x    = (const float*)d_in[0];  // [B*S, D] fp32
  const float* Wqkv = (const float*)d_in[1];  // [3D, D]  fp32
  const float* Wo   = (const float*)d_in[2];  // [D, D]   fp32
  float* out = (float*)d_out;                 // [B*S, D] fp32

  const int Bn = 4, S = 4096, D = 1024;
  const int M = Bn * S;  // 16384
  const int E = 3 * D;   // 3072
  const long SE = (long)S * E, SS = (long)S * S, DS = (long)D * S, SD = (long)S * D;

  // Batched (grid.z=4) path needs 4x Sbuf + 4x Vt: gate on ws_size; both
  // paths are call-invariant since ws_size is constant for the session.
  const size_t need4 = 310378496;  // 296 MB
  const int nb = (ws_size >= need4) ? 4 : 1;

  char* ws = (char*)d_ws;
  size_t off = 0;
  u16* qkv = (u16*)(ws + off);  off += (size_t)M * E * 2;        // 96 MB
  u16* Sb  = (u16*)(ws + off);  off += (size_t)nb * S * S * 2;   // nb*32 MB
  u16* Vt  = (u16*)(ws + off);  off += (size_t)nb * D * S * 2;   // nb*8 MB
  u16* xb  = (u16*)(ws + off);  off += (size_t)M * D * 2;        // 32 MB
  u16* attn = xb;                 // xb dead after QKV proj
  u16* Wqkvb = (u16*)(ws + off); off += (size_t)E * D * 2;       // 6 MB
  u16* Wob   = (u16*)(ws + off); off += (size_t)D * D * 2;       // 2 MB
  // rowsum [4][4096] fp32 aliases Wqkvb: Wqkvb dead after QKV gemm,
  // rs first written by rowsum_rows which launches after it. 64 KB.
  float* rs = (float*)Wqkvb;

  // 0) fp32 -> bf16 converts
  cvt_f32_bf16<<<(M * D / 8 + 255) / 256, 256, 0, stream>>>(x, xb, M * D / 8);
  cvt_f32_bf16<<<(E * D / 8 + 255) / 256, 256, 0, stream>>>(Wqkv, Wqkvb, E * D / 8);
  cvt_f32_bf16<<<(D * D / 8 + 255) / 256, 256, 0, stream>>>(Wo, Wob, D * D / 8);

  // 1) QKV projection: qkv = xb @ Wqkvb^T   [16384 x 3072]
  gemm_bt<u16, 0><<<dim3(E / 128, M / 128, 1), 256, 0, stream>>>(
      xb, D, 0, Wqkvb, D, 0, qkv, E, 0, D, 1.0f, nullptr);

  const float scl = 0.03125f;  // 1/sqrt(1024)
  if (nb == 4) {
    // 2) P = exp(Q K^T / 32), unnormalized, all batches
    gemm_bt<u16, 1><<<dim3(S / 128, S / 128, 4), 256, 0, stream>>>(
        qkv, E, SE, qkv + D, E, SE, Sb, S, SS, D, scl, nullptr);
    // 3) rs[z][row] = sum_k P[z][row][k]
    rowsum_rows<<<dim3(S, 4), 256, 0, stream>>>(Sb, SS, rs);
    // 4) Vt = V^T
    transpose_v<<<dim3(D / 64, S / 64, 4), 256, 0, stream>>>(
        qkv + 2 * D, E, SE, Vt, S, DS);
    // 5) attn = (P @ V) / rs
    gemm_bt<u16, 2><<<dim3(D / 128, S / 128, 4), 256, 0, stream>>>(
        Sb, S, SS, Vt, S, DS, attn, D, SD, S, 1.0f, rs);
  } else {
    for (int b = 0; b < Bn; ++b) {
      const u16* Qb = qkv + (size_t)b * SE;
      gemm_bt<u16, 1><<<dim3(S / 128, S / 128, 1), 256, 0, stream>>>(
          Qb, E, 0, Qb + D, E, 0, Sb, S, 0, D, scl, nullptr);
      rowsum_rows<<<dim3(S, 1), 256, 0, stream>>>(Sb, 0, rs);
      transpose_v<<<dim3(D / 64, S / 64, 1), 256, 0, stream>>>(
          Qb + 2 * D, E, 0, Vt, S, 0);
      gemm_bt<u16, 2><<<dim3(D / 128, S / 128, 1), 256, 0, stream>>>(
          Sb, S, 0, Vt, S, 0, attn + (size_t)b * SD, D, 0, S, 1.0f, rs);
    }
  }
  // 6) out = attn @ Wo^T  [16384 x 1024] -> fp32
  gemm_bt<float, 0><<<dim3(D / 128, M / 128, 1), 256, 0, stream>>>(
      attn, D, 0, Wob, D, 0, out, D, 0, D, 1.0f, nullptr);
}